// Round 11
// baseline (209.708 us; speedup 1.0000x reference)
//
#include <hip/hip_runtime.h>

#define EPS 1e-8f

using short8 = __attribute__((ext_vector_type(8))) short;
using f32x16 = __attribute__((ext_vector_type(16))) float;
typedef unsigned short u16;

#define WAITV(N) asm volatile("s_waitcnt vmcnt(" #N ")" ::: "memory")
#define BARRIER() do { __builtin_amdgcn_s_barrier(); \
                       asm volatile("" ::: "memory"); } while (0)

__device__ __forceinline__ u16 f2bf(float f) {
    union { float f; unsigned u; } v; v.f = f;
    unsigned u = v.u;
    return (u16)((u + 0x7FFFu + ((u >> 16) & 1u)) >> 16);
}

__device__ __forceinline__ void g2l16(const void* gsrc, void* ldst) {
    __builtin_amdgcn_global_load_lds(
        (const __attribute__((address_space(1))) unsigned int*)gsrc,
        (__attribute__((address_space(3))) unsigned int*)ldst, 16, 0, 0);
}

// ---------------- kernel 1: style[b][i] = dot(w[b], affine_w[i]) + affine_b[i] + 1
__global__ void style_kernel(const float* __restrict__ w,        // [8][512]
                             const float* __restrict__ affine_w, // [256][512]
                             const float* __restrict__ affine_b, // [256]
                             float* __restrict__ style) {        // [8][256]
    int b = blockIdx.x;
    int i = threadIdx.x;
    __shared__ float wb[512];
    for (int z = threadIdx.x; z < 512; z += 256) wb[z] = w[b * 512 + z];
    __syncthreads();
    const float* aw = affine_w + i * 512;
    float acc = 0.f;
#pragma unroll 4
    for (int z = 0; z < 512; z += 4) {
        float4 a4 = *reinterpret_cast<const float4*>(aw + z);
        acc += a4.x * wb[z] + a4.y * wb[z + 1] + a4.z * wb[z + 2] + a4.w * wb[z + 3];
    }
    style[b * 256 + i] = acc + affine_b[i] + 1.0f;
}

// ---------------- kernel 2: modulate + demodulate, pack bf16 weights
// wgt layout: bf16 [b][t(9)][g(32)][o(256)][j(8)], ic = g*8 + j
__global__ void modw_kernel(const float* __restrict__ weight, // [256][256][3][3]
                            const float* __restrict__ style,  // [8][256]
                            u16* __restrict__ wgt) {
    int b = blockIdx.x >> 8;
    int o = blockIdx.x & 255;
    int ic = threadIdx.x; // 256 threads
    float s = style[b * 256 + ic];
    const float* wp = weight + (size_t)(o * 256 + ic) * 9;
    float m[9];
    float ss = 0.f;
#pragma unroll
    for (int t = 0; t < 9; ++t) { m[t] = wp[t] * s; ss += m[t] * m[t]; }
#pragma unroll
    for (int off = 32; off > 0; off >>= 1) ss += __shfl_down(ss, off);
    __shared__ float part[4];
    int lane = threadIdx.x & 63, wid = threadIdx.x >> 6;
    if (lane == 0) part[wid] = ss;
    __syncthreads();
    float denom = rsqrtf(part[0] + part[1] + part[2] + part[3] + EPS);
    int g = ic >> 3, j = ic & 7;
#pragma unroll
    for (int t = 0; t < 9; ++t) {
        size_t idx = ((((size_t)(b * 9 + t) * 32 + g) * 256 + o) << 3) + j;
        wgt[idx] = f2bf(m[t] * denom);
    }
}

// ---------------- kernel 3: x fp32 [8][256][128][128] -> bf16 xb [8][32][128][128][8]
__global__ __launch_bounds__(256) void xform_kernel(const float* __restrict__ x,
                                                    u16* __restrict__ xb) {
    int s = blockIdx.x * 256 + threadIdx.x; // (b,g,h,w)
    int w = s & 127, h = (s >> 7) & 127, g = (s >> 14) & 31, b = s >> 19;
    const float* xp = x + (((size_t)(b * 256 + g * 8) * 128 + h) * 128 + w);
    union { u16 u[8]; short8 v; } pk;
#pragma unroll
    for (int j = 0; j < 8; ++j) pk.u[j] = f2bf(xp[(size_t)j * 16384]);
    *reinterpret_cast<short8*>(&xb[(size_t)s * 8]) = pk.v;
}

// ---------------- kernel 4: implicit-GEMM conv, 32x32x16 MFMA, occupancy-first
// block = (b, ot, ht): 128 o x (2 rows x 128 w), 512 threads (8 waves).
// Wave (wm,wr,wn) -> 64o x 64w x 1 row sub-tile: acc = 2x2 frags = 64 VGPR.
// Target 4 waves/SIMD (16 waves/CU) via __launch_bounds__(512,4): regs <= 128.
// A: global->VGPR dist-1 prefetch (afC/afN); dup loads across (wr,wn) hit L1.
// X: LDS double-buffer, staged via global_load_lds at t0 (after afN issue; the
//    forced X-drain at t+2 is ~3000 wall-cycles after issue >> HBM latency).
// One WAITV(4)+barrier per chunk. Grid 1024x512 = exactly 2 blocks/CU, 2 passes.
__global__ __launch_bounds__(512, 4) void conv_kernel(
    const u16* __restrict__ xb,  // [8][32][128][128][8] bf16
    const u16* __restrict__ wgt, // [8][9][32][256][8] bf16
    float* __restrict__ out) {   // [8][256][128][128]

    __shared__ __align__(16) u16 Xs[2][4][4][130][8]; // 66560 B [buf][row][g][w130][j8]
    __shared__ __align__(16) u16 trash[1024];         // OOB-row sink

    int bid = blockIdx.x;
    int swz = (bid & 7) * 128 + (bid >> 3); // grid 1024 = 8*128, bijective
    int ht = swz & 63, ot = (swz >> 6) & 1, b = swz >> 7;
    int h0 = ht * 2;

    int tid = threadIdx.x, lane = tid & 63, wid = tid >> 6;
    int wm = wid >> 2, wr = (wid >> 1) & 1, wn = wid & 1; // o-half, row, w-half
    int l31 = lane & 31, lh = lane >> 5;

    // staging role: wave stages row srow (2 waves/row, split by g-pair)
    int srow = wid >> 1, gsel = wid & 1;
    int hr = h0 + srow - 1;
    bool hValid = ((unsigned)hr < 128u);
    int hc = hValid ? hr : 0;

    // per-lane A base: (b, t=0, g=lh, o = ot*128 + wm*64 + l31)
    const u16* aBase = wgt + ((size_t)(b * 9) * 32 * 256 +
                              (size_t)(lh * 256 + ot * 128 + wm * 64 + l31)) * 8;

    auto loadA = [&](short8 dst[2][2], int c, int t) {
#pragma unroll
        for (int kk = 0; kk < 2; ++kk)
#pragma unroll
            for (int mi = 0; mi < 2; ++mi)
                dst[kk][mi] = *reinterpret_cast<const short8*>(
                    aBase + (size_t)(((t * 32) + c * 4 + kk * 2) * 256 + mi * 32) * 8);
    };
    auto stageX = [&](int c1, int bx) { // 4 x 1KB g2l16 per wave
#pragma unroll
        for (int k = 0; k < 4; ++k) {
            int g = gsel * 2 + (k >> 1), half = k & 1;
            const u16* src = xb +
                ((((size_t)(b * 32 + c1 * 4 + g)) * 128 + hc) * 128 + half * 64 + lane) * 8;
            void* dst = hValid ? (void*)&Xs[bx][srow][g][1 + half * 64][0] : (void*)trash;
            g2l16(src, dst);
        }
    };

    // zero both X buffers (borders + OOB rows stay zero forever)
    {
        short8 z = {0, 0, 0, 0, 0, 0, 0, 0};
        short8* p0 = reinterpret_cast<short8*>(&Xs[0][0][0][0][0]);
        for (int i = tid; i < 4160; i += 512) p0[i] = z;
    }
    __syncthreads();

    short8 afC[2][2], afN[2][2];
    stageX(0, 0);          // X chunk 0 (oldest in FIFO)
    loadA(afC, 0, 0);
    WAITV(4);              // drain X0; leave afC
    BARRIER();

    f32x16 acc[2][2] = {};

    for (int c = 0; c < 8; ++c) {
        int buf = c & 1;
#pragma unroll
        for (int t = 0; t < 9; ++t) {
            bool lastTap = (c == 7 && t == 8);
            if (!lastTap)
                loadA(afN, t < 8 ? c : c + 1, t < 8 ? t + 1 : 0);
            if (t == 0 && c < 7) stageX(c + 1, buf ^ 1);

            int kh = t / 3, kw = t - kh * 3;
            __builtin_amdgcn_s_setprio(1);
#pragma unroll
            for (int kk = 0; kk < 2; ++kk) {
                short8 bxv[2];
#pragma unroll
                for (int ni = 0; ni < 2; ++ni)
                    bxv[ni] = *reinterpret_cast<const short8*>(
                        &Xs[buf][wr + kh][kk * 2 + lh][wn * 64 + ni * 32 + l31 + kw][0]);
#pragma unroll
                for (int mi = 0; mi < 2; ++mi)
#pragma unroll
                    for (int ni = 0; ni < 2; ++ni)
                        acc[mi][ni] = __builtin_amdgcn_mfma_f32_32x32x16_bf16(
                            afC[kk][mi], bxv[ni], acc[mi][ni], 0, 0, 0);
            }
            __builtin_amdgcn_s_setprio(0);

            if (!lastTap) {
#pragma unroll
                for (int k2 = 0; k2 < 2; ++k2)
#pragma unroll
                    for (int mi = 0; mi < 2; ++mi)
                        afC[k2][mi] = afN[k2][mi];
            }
        }
        if (c < 7) { WAITV(4); BARRIER(); } // X(c+1) landed block-wide; afN stays in flight
    }

    // epilogue: C/D 32x32 layout col=lane&31 (w), row=(reg&3)+8*(reg>>2)+4*(lane>>5) (o)
    int h = h0 + wr;
#pragma unroll
    for (int mi = 0; mi < 2; ++mi) {
        int ob = ot * 128 + wm * 64 + mi * 32 + 4 * lh;
#pragma unroll
        for (int ni = 0; ni < 2; ++ni) {
            int w_ = wn * 64 + ni * 32 + l31;
#pragma unroll
            for (int reg = 0; reg < 16; ++reg) {
                int o = ob + (reg & 3) + 8 * (reg >> 2);
                out[(((size_t)(b * 256 + o) * 128 + h) * 128) + w_] = acc[mi][ni][reg];
            }
        }
    }
}

extern "C" void kernel_launch(void* const* d_in, const int* in_sizes, int n_in,
                              void* d_out, int out_size, void* d_ws, size_t ws_size,
                              hipStream_t stream) {
    const float* x        = (const float*)d_in[0];
    const float* w        = (const float*)d_in[1];
    const float* weight   = (const float*)d_in[2];
    const float* affine_w = (const float*)d_in[3];
    const float* affine_b = (const float*)d_in[4];
    float* out = (float*)d_out;

    float* style = (float*)d_ws;                                   // 8 KB
    u16* wgt = (u16*)((char*)d_ws + 8192);                         // 9.44 MB
    u16* xbuf = (u16*)((char*)d_ws + 8192 + 9437184);              // 64 MB

    xform_kernel<<<16384, 256, 0, stream>>>(x, xbuf);
    style_kernel<<<8, 256, 0, stream>>>(w, affine_w, affine_b, style);
    modw_kernel<<<2048, 256, 0, stream>>>(weight, style, wgt);
    conv_kernel<<<1024, 512, 0, stream>>>(xbuf, wgt, out);
}

// Round 12
// 183.715 us; speedup vs baseline: 1.1415x; 1.1415x over previous
//
#include <hip/hip_runtime.h>

#define EPS 1e-8f

using short8 = __attribute__((ext_vector_type(8))) short;
using f32x16 = __attribute__((ext_vector_type(16))) float;
typedef unsigned short u16;

#define BARRIER() do { __builtin_amdgcn_s_barrier(); \
                       asm volatile("" ::: "memory"); } while (0)
#define LGKM0() asm volatile("s_waitcnt lgkmcnt(0)" ::: "memory")

__device__ __forceinline__ u16 f2bf(float f) {
    union { float f; unsigned u; } v; v.f = f;
    unsigned u = v.u;
    return (u16)((u + 0x7FFFu + ((u >> 16) & 1u)) >> 16);
}

// ---------------- kernel 1: style[b][i] = dot(w[b], affine_w[i]) + affine_b[i] + 1
__global__ void style_kernel(const float* __restrict__ w,        // [8][512]
                             const float* __restrict__ affine_w, // [256][512]
                             const float* __restrict__ affine_b, // [256]
                             float* __restrict__ style) {        // [8][256]
    int b = blockIdx.x;
    int i = threadIdx.x;
    __shared__ float wb[512];
    for (int z = threadIdx.x; z < 512; z += 256) wb[z] = w[b * 512 + z];
    __syncthreads();
    const float* aw = affine_w + i * 512;
    float acc = 0.f;
#pragma unroll 4
    for (int z = 0; z < 512; z += 4) {
        float4 a4 = *reinterpret_cast<const float4*>(aw + z);
        acc += a4.x * wb[z] + a4.y * wb[z + 1] + a4.z * wb[z + 2] + a4.w * wb[z + 3];
    }
    style[b * 256 + i] = acc + affine_b[i] + 1.0f;
}

// ---------------- kernel 2: modulate + demodulate, pack bf16 weights
// wgt layout: bf16 [b][t(9)][g(32)][o(256)][j(8)], ic = g*8 + j
__global__ void modw_kernel(const float* __restrict__ weight, // [256][256][3][3]
                            const float* __restrict__ style,  // [8][256]
                            u16* __restrict__ wgt) {
    int b = blockIdx.x >> 8;
    int o = blockIdx.x & 255;
    int ic = threadIdx.x; // 256 threads
    float s = style[b * 256 + ic];
    const float* wp = weight + (size_t)(o * 256 + ic) * 9;
    float m[9];
    float ss = 0.f;
#pragma unroll
    for (int t = 0; t < 9; ++t) { m[t] = wp[t] * s; ss += m[t] * m[t]; }
#pragma unroll
    for (int off = 32; off > 0; off >>= 1) ss += __shfl_down(ss, off);
    __shared__ float part[4];
    int lane = threadIdx.x & 63, wid = threadIdx.x >> 6;
    if (lane == 0) part[wid] = ss;
    __syncthreads();
    float denom = rsqrtf(part[0] + part[1] + part[2] + part[3] + EPS);
    int g = ic >> 3, j = ic & 7;
#pragma unroll
    for (int t = 0; t < 9; ++t) {
        size_t idx = ((((size_t)(b * 9 + t) * 32 + g) * 256 + o) << 3) + j;
        wgt[idx] = f2bf(m[t] * denom);
    }
}

// ---------------- kernel 3: fused implicit-GEMM conv (xform folded in)
// block = (b, ot, ht): 128 o x (2 rows x 128 w), 256 threads (4 waves), 2 blocks/CU.
// A: global->VGPR per wave (L2-resident), 1-tap prefetch afC/afN (R9 scheme).
// X: read DIRECTLY from fp32 x, converted in-register to bf16, ds_write_b128
//    into the double-buffered Xs. Batch bt (8 coalesced dword loads) issued at
//    tap t=bt, converted+written at tap t+1 -> HBM latency hides under a tap
//    of MFMA (T14). FIFO: loadA -> issueX(t) -> writeX(t-1): the forced wait
//    for batch t-1 leaves afN + batch t in flight. No manual vmcnt needed.
// Chunk boundary: lgkmcnt(0) + barrier. OOB-row waves never write (zeros persist).
__global__ __launch_bounds__(256, 2) void conv_kernel(
    const float* __restrict__ x,  // [8][256][128][128] fp32
    const u16* __restrict__ wgt,  // [8][9][32][256][8] bf16
    float* __restrict__ out) {    // [8][256][128][128]

    __shared__ __align__(16) u16 Xs[2][4][4][130][8]; // 66560 B [buf][row][g][w130][j8]

    int bid = blockIdx.x;
    int swz = (bid & 7) * 128 + (bid >> 3); // grid 1024 = 8*128, bijective
    int ht = swz & 63, ot = (swz >> 6) & 1, b = swz >> 7;
    int h0 = ht * 2;

    int tid = threadIdx.x, lane = tid & 63, wid = tid >> 6;
    int wm = wid >> 1, wr = wid & 1; // wave -> (o half 64, row)
    int l31 = lane & 31, lh = lane >> 5;

    int hr = h0 + wid - 1;
    bool hValid = ((unsigned)hr < 128u);
    int hc = hValid ? hr : 0;

    // per-lane bases
    const u16* aBase = wgt + ((size_t)(b * 9) * 32 * 256 +
                              (size_t)(lh * 256 + ot * 128 + wm * 64 + l31)) * 8;
    const float* xBase = x + ((size_t)(b * 256) * 128 + hc) * 128; // + ic*16384 + w

    auto loadA = [&](short8 dst[2][2], int c, int t) {
#pragma unroll
        for (int kk = 0; kk < 2; ++kk)
#pragma unroll
            for (int mi = 0; mi < 2; ++mi)
                dst[kk][mi] = *reinterpret_cast<const short8*>(
                    aBase + (size_t)(((t * 32) + c * 4 + kk * 2) * 256 + mi * 32) * 8);
    };
    // batch bt of chunk c1: g = bt>>1, half = bt&1; 8 coalesced dword loads
    auto issueX = [&](float* dst, int c1, int bt) {
        int g = bt >> 1, half = bt & 1;
        const float* sp = xBase + (size_t)(c1 * 32 + g * 8) * 16384 + half * 64 + lane;
#pragma unroll
        for (int j = 0; j < 8; ++j) dst[j] = sp[(size_t)j * 16384];
    };
    auto writeX = [&](const float* src, int bt, int bx) {
        int g = bt >> 1, half = bt & 1;
        union { u16 u[8]; short8 v; } pk;
#pragma unroll
        for (int j = 0; j < 8; ++j) pk.u[j] = f2bf(src[j]);
        *reinterpret_cast<short8*>(&Xs[bx][wid][g][1 + half * 64 + lane][0]) = pk.v;
    };

    // zero both X buffers (borders + OOB rows stay zero forever)
    {
        short8 z = {0, 0, 0, 0, 0, 0, 0, 0};
        short8* p0 = reinterpret_cast<short8*>(&Xs[0][0][0][0][0]);
        for (int i = tid; i < 4160; i += 256) p0[i] = z;
    }
    __syncthreads();

    short8 afC[2][2], afN[2][2];
    // prologue: stage chunk 0 into buf 0 (all 8 batches in flight, then write)
    if (hValid) {
        float xg0[8][8];
#pragma unroll
        for (int bt = 0; bt < 8; ++bt) issueX(xg0[bt], 0, bt);
#pragma unroll
        for (int bt = 0; bt < 8; ++bt) writeX(xg0[bt], bt, 0);
    }
    loadA(afC, 0, 0);
    LGKM0();
    BARRIER();

    f32x16 acc[2][4] = {};
    float xg[2][8]; // ping-pong staging batches (statically indexed under unroll)

    for (int c = 0; c < 8; ++c) {
        int buf = c & 1;
        bool stage = (c < 7) && hValid;
#pragma unroll
        for (int t = 0; t < 9; ++t) {
            bool lastTap = (c == 7 && t == 8);
            if (!lastTap)
                loadA(afN, t < 8 ? c : c + 1, t < 8 ? t + 1 : 0);
            if (stage) {
                if (t < 8) issueX(xg[t & 1], c + 1, t);
                if (t > 0) writeX(xg[(t - 1) & 1], t - 1, buf ^ 1);
            }

            int kh = t / 3, kw = t - kh * 3;
            short8 bx8[2][4];
#pragma unroll
            for (int kk = 0; kk < 2; ++kk)
#pragma unroll
                for (int ni = 0; ni < 4; ++ni)
                    bx8[kk][ni] = *reinterpret_cast<const short8*>(
                        &Xs[buf][wr + kh][kk * 2 + lh][ni * 32 + l31 + kw][0]);
            __builtin_amdgcn_s_setprio(1);
#pragma unroll
            for (int mi = 0; mi < 2; ++mi)
#pragma unroll
                for (int ni = 0; ni < 4; ++ni)
#pragma unroll
                    for (int kk = 0; kk < 2; ++kk)
                        acc[mi][ni] = __builtin_amdgcn_mfma_f32_32x32x16_bf16(
                            afC[kk][mi], bx8[kk][ni], acc[mi][ni], 0, 0, 0);
            __builtin_amdgcn_s_setprio(0);

            if (!lastTap) {
#pragma unroll
                for (int k2 = 0; k2 < 2; ++k2)
#pragma unroll
                    for (int mi = 0; mi < 2; ++mi)
                        afC[k2][mi] = afN[k2][mi];
            }
        }
        if (c < 7) { LGKM0(); BARRIER(); } // ds_writes of chunk c+1 visible block-wide
    }

    // epilogue: C/D 32x32 layout col=lane&31 (w), row=(reg&3)+8*(reg>>2)+4*(lane>>5) (o)
    int h = h0 + wr;
#pragma unroll
    for (int mi = 0; mi < 2; ++mi) {
        int ob = ot * 128 + wm * 64 + mi * 32 + 4 * lh;
#pragma unroll
        for (int ni = 0; ni < 4; ++ni) {
            int w_ = ni * 32 + l31;
#pragma unroll
            for (int reg = 0; reg < 16; ++reg) {
                int o = ob + (reg & 3) + 8 * (reg >> 2);
                out[(((size_t)(b * 256 + o) * 128 + h) * 128) + w_] = acc[mi][ni][reg];
            }
        }
    }
}

extern "C" void kernel_launch(void* const* d_in, const int* in_sizes, int n_in,
                              void* d_out, int out_size, void* d_ws, size_t ws_size,
                              hipStream_t stream) {
    const float* x        = (const float*)d_in[0];
    const float* w        = (const float*)d_in[1];
    const float* weight   = (const float*)d_in[2];
    const float* affine_w = (const float*)d_in[3];
    const float* affine_b = (const float*)d_in[4];
    float* out = (float*)d_out;

    float* style = (float*)d_ws;                                   // 8 KB
    u16* wgt = (u16*)((char*)d_ws + 8192);                         // 9.44 MB

    style_kernel<<<8, 256, 0, stream>>>(w, affine_w, affine_b, style);
    modw_kernel<<<2048, 256, 0, stream>>>(weight, style, wgt);
    conv_kernel<<<1024, 256, 0, stream>>>(x, wgt, out);
}

// Round 13
// 182.850 us; speedup vs baseline: 1.1469x; 1.0047x over previous
//
#include <hip/hip_runtime.h>
#include <hip/hip_bf16.h>

#define EPS 1e-8f

using short8 = __attribute__((ext_vector_type(8))) short;
using f32x16 = __attribute__((ext_vector_type(16))) float;
typedef unsigned short u16;

#define BARRIER() do { __builtin_amdgcn_s_barrier(); \
                       asm volatile("" ::: "memory"); } while (0)
#define LGKM0() asm volatile("s_waitcnt lgkmcnt(0)" ::: "memory")

__device__ __forceinline__ u16 f2bf(float f) {
    union { float f; unsigned u; } v; v.f = f;
    unsigned u = v.u;
    return (u16)((u + 0x7FFFu + ((u >> 16) & 1u)) >> 16);
}

// ---------------- kernel 1: style[b][i] = dot(w[b], affine_w[i]) + affine_b[i] + 1
__global__ void style_kernel(const float* __restrict__ w,        // [8][512]
                             const float* __restrict__ affine_w, // [256][512]
                             const float* __restrict__ affine_b, // [256]
                             float* __restrict__ style) {        // [8][256]
    int b = blockIdx.x;
    int i = threadIdx.x;
    __shared__ float wb[512];
    for (int z = threadIdx.x; z < 512; z += 256) wb[z] = w[b * 512 + z];
    __syncthreads();
    const float* aw = affine_w + i * 512;
    float acc = 0.f;
#pragma unroll 4
    for (int z = 0; z < 512; z += 4) {
        float4 a4 = *reinterpret_cast<const float4*>(aw + z);
        acc += a4.x * wb[z] + a4.y * wb[z + 1] + a4.z * wb[z + 2] + a4.w * wb[z + 3];
    }
    style[b * 256 + i] = acc + affine_b[i] + 1.0f;
}

// ---------------- kernel 2: modulate + demodulate, pack bf16 weights
// wgt layout: bf16 [b][t(9)][g(32)][o(256)][j(8)], ic = g*8 + j
__global__ void modw_kernel(const float* __restrict__ weight, // [256][256][3][3]
                            const float* __restrict__ style,  // [8][256]
                            u16* __restrict__ wgt) {
    int b = blockIdx.x >> 8;
    int o = blockIdx.x & 255;
    int ic = threadIdx.x; // 256 threads
    float s = style[b * 256 + ic];
    const float* wp = weight + (size_t)(o * 256 + ic) * 9;
    float m[9];
    float ss = 0.f;
#pragma unroll
    for (int t = 0; t < 9; ++t) { m[t] = wp[t] * s; ss += m[t] * m[t]; }
#pragma unroll
    for (int off = 32; off > 0; off >>= 1) ss += __shfl_down(ss, off);
    __shared__ float part[4];
    int lane = threadIdx.x & 63, wid = threadIdx.x >> 6;
    if (lane == 0) part[wid] = ss;
    __syncthreads();
    float denom = rsqrtf(part[0] + part[1] + part[2] + part[3] + EPS);
    int g = ic >> 3, j = ic & 7;
#pragma unroll
    for (int t = 0; t < 9; ++t) {
        size_t idx = ((((size_t)(b * 9 + t) * 32 + g) * 256 + o) << 3) + j;
        wgt[idx] = f2bf(m[t] * denom);
    }
}

// ---------------- kernel 3: fused implicit-GEMM conv (xform folded in)
// block = (b, ot, ht): 128 o x (2 rows x 128 w), 256 threads (4 waves), 2 blocks/CU.
// A: global->VGPR per wave (L2-resident), 1-tap prefetch afC/afN.
// X: fp32 x read directly; DISTANCE-2 staging (T14 depth 2): batch t issued at
//    tap t, converted (native __float2bfloat16 -> v_cvt_pk fusion) + ds_written
//    at tap t+2. 2-slot ping-pong: write frees slot t&1, issue refills it (WAR
//    on VGPRs orders it). Cover ~1400 cyc > 900 HBM latency -> no per-tap stall.
//    Batch 7 written at t==8 (1-tap cover, once per chunk).
// Chunk boundary: lgkmcnt(0) + barrier. OOB-row waves never write (zeros persist).
__global__ __launch_bounds__(256, 2) void conv_kernel(
    const float* __restrict__ x,  // [8][256][128][128] fp32
    const u16* __restrict__ wgt,  // [8][9][32][256][8] bf16
    float* __restrict__ out) {    // [8][256][128][128]

    __shared__ __align__(16) u16 Xs[2][4][4][130][8]; // 66560 B [buf][row][g][w130][j8]

    int bid = blockIdx.x;
    int swz = (bid & 7) * 128 + (bid >> 3); // grid 1024 = 8*128, bijective
    int ht = swz & 63, ot = (swz >> 6) & 1, b = swz >> 7;
    int h0 = ht * 2;

    int tid = threadIdx.x, lane = tid & 63, wid = tid >> 6;
    int wm = wid >> 1, wr = wid & 1; // wave -> (o half 64, row)
    int l31 = lane & 31, lh = lane >> 5;

    int hr = h0 + wid - 1;
    bool hValid = ((unsigned)hr < 128u);
    int hc = hValid ? hr : 0;

    // per-lane bases
    const u16* aBase = wgt + ((size_t)(b * 9) * 32 * 256 +
                              (size_t)(lh * 256 + ot * 128 + wm * 64 + l31)) * 8;
    const float* xBase = x + ((size_t)(b * 256) * 128 + hc) * 128; // + ic*16384 + w

    auto loadA = [&](short8 dst[2][2], int c, int t) {
#pragma unroll
        for (int kk = 0; kk < 2; ++kk)
#pragma unroll
            for (int mi = 0; mi < 2; ++mi)
                dst[kk][mi] = *reinterpret_cast<const short8*>(
                    aBase + (size_t)(((t * 32) + c * 4 + kk * 2) * 256 + mi * 32) * 8);
    };
    // batch bt of chunk c1: g = bt>>1, half = bt&1; 8 coalesced dword loads
    auto issueX = [&](float* dst, int c1, int bt) {
        int g = bt >> 1, half = bt & 1;
        const float* sp = xBase + (size_t)(c1 * 32 + g * 8) * 16384 + half * 64 + lane;
#pragma unroll
        for (int j = 0; j < 8; ++j) dst[j] = sp[(size_t)j * 16384];
    };
    auto writeX = [&](const float* src, int bt, int bx) {
        int g = bt >> 1, half = bt & 1;
        union { u16 u[8]; short8 v; } pk;
#pragma unroll
        for (int j = 0; j < 8; ++j) {
            __hip_bfloat16 hb = __float2bfloat16(src[j]);
            pk.u[j] = reinterpret_cast<u16&>(hb);
        }
        *reinterpret_cast<short8*>(&Xs[bx][wid][g][1 + half * 64 + lane][0]) = pk.v;
    };

    // zero both X buffers (borders + OOB rows stay zero forever)
    {
        short8 z = {0, 0, 0, 0, 0, 0, 0, 0};
        short8* p0 = reinterpret_cast<short8*>(&Xs[0][0][0][0][0]);
        for (int i = tid; i < 4160; i += 256) p0[i] = z;
    }
    __syncthreads();

    short8 afC[2][2], afN[2][2];
    // prologue: stage chunk 0 into buf 0 (all 8 batches in flight, then write)
    if (hValid) {
        float xg0[8][8];
#pragma unroll
        for (int bt = 0; bt < 8; ++bt) issueX(xg0[bt], 0, bt);
#pragma unroll
        for (int bt = 0; bt < 8; ++bt) writeX(xg0[bt], bt, 0);
    }
    loadA(afC, 0, 0);
    LGKM0();
    BARRIER();

    f32x16 acc[2][4] = {};
    float xg[2][8]; // ping-pong staging batches (statically indexed under unroll)

    for (int c = 0; c < 8; ++c) {
        int buf = c & 1;
        bool stage = (c < 7) && hValid;
#pragma unroll
        for (int t = 0; t < 9; ++t) {
            bool lastTap = (c == 7 && t == 8);
            if (!lastTap)
                loadA(afN, t < 8 ? c : c + 1, t < 8 ? t + 1 : 0);
            if (stage) {
                if (t >= 2) writeX(xg[t & 1], t - 2, buf ^ 1);   // batch t-2, slot (t-2)&1 == t&1
                if (t < 8)  issueX(xg[t & 1], c + 1, t);         // refill freed slot
                if (t == 8) writeX(xg[1], 7, buf ^ 1);           // batch 7 (1-tap cover)
            }

            int kh = t / 3, kw = t - kh * 3;
            short8 bx8[2][4];
#pragma unroll
            for (int kk = 0; kk < 2; ++kk)
#pragma unroll
                for (int ni = 0; ni < 4; ++ni)
                    bx8[kk][ni] = *reinterpret_cast<const short8*>(
                        &Xs[buf][wr + kh][kk * 2 + lh][ni * 32 + l31 + kw][0]);
            __builtin_amdgcn_s_setprio(1);
#pragma unroll
            for (int mi = 0; mi < 2; ++mi)
#pragma unroll
                for (int ni = 0; ni < 4; ++ni)
#pragma unroll
                    for (int kk = 0; kk < 2; ++kk)
                        acc[mi][ni] = __builtin_amdgcn_mfma_f32_32x32x16_bf16(
                            afC[kk][mi], bx8[kk][ni], acc[mi][ni], 0, 0, 0);
            __builtin_amdgcn_s_setprio(0);

            if (!lastTap) {
#pragma unroll
                for (int k2 = 0; k2 < 2; ++k2)
#pragma unroll
                    for (int mi = 0; mi < 2; ++mi)
                        afC[k2][mi] = afN[k2][mi];
            }
        }
        if (c < 7) { LGKM0(); BARRIER(); } // ds_writes of chunk c+1 visible block-wide
    }

    // epilogue: C/D 32x32 layout col=lane&31 (w), row=(reg&3)+8*(reg>>2)+4*(lane>>5) (o)
    int h = h0 + wr;
#pragma unroll
    for (int mi = 0; mi < 2; ++mi) {
        int ob = ot * 128 + wm * 64 + mi * 32 + 4 * lh;
#pragma unroll
        for (int ni = 0; ni < 4; ++ni) {
            int w_ = ni * 32 + l31;
#pragma unroll
            for (int reg = 0; reg < 16; ++reg) {
                int o = ob + (reg & 3) + 8 * (reg >> 2);
                out[(((size_t)(b * 256 + o) * 128 + h) * 128) + w_] = acc[mi][ni][reg];
            }
        }
    }
}

extern "C" void kernel_launch(void* const* d_in, const int* in_sizes, int n_in,
                              void* d_out, int out_size, void* d_ws, size_t ws_size,
                              hipStream_t stream) {
    const float* x        = (const float*)d_in[0];
    const float* w        = (const float*)d_in[1];
    const float* weight   = (const float*)d_in[2];
    const float* affine_w = (const float*)d_in[3];
    const float* affine_b = (const float*)d_in[4];
    float* out = (float*)d_out;

    float* style = (float*)d_ws;                                   // 8 KB
    u16* wgt = (u16*)((char*)d_ws + 8192);                         // 9.44 MB

    style_kernel<<<8, 256, 0, stream>>>(w, affine_w, affine_b, style);
    modw_kernel<<<2048, 256, 0, stream>>>(weight, style, wgt);
    conv_kernel<<<1024, 256, 0, stream>>>(x, wgt, out);
}